// Round 6
// baseline (56.442 us; speedup 1.0000x reference)
//
#include <hip/hip_runtime.h>
#include <hip/hip_bf16.h>

typedef __attribute__((ext_vector_type(8))) short short8;
typedef __attribute__((ext_vector_type(4))) float f32x4;
typedef unsigned short u16;
typedef unsigned int u32;

#define NROWS 8192
#define HALF  4096
#define DIM   256
#define TEMP_INV 2.0f   // 1/temperature
#define BK 32
#define NBT 64                        // 8192/128 tiles per side
#define NTILE (NBT * (NBT + 1) / 2)   // 2080 triangular tiles
#define TPB 4                         // tiles per block
#define NBLK (NTILE / TPB)            // 520 blocks -> all resident
#define NSLAB 128                     // 64 tiles * 2 wave-halves

#define BARRIER() asm volatile("s_barrier" ::: "memory")
#define WAITV(n)  asm volatile("s_waitcnt vmcnt(" #n ")" ::: "memory")

__device__ __forceinline__ u16 f2bf(float f) {
    union { float f; u32 i; } c; c.f = f;
    u32 lsb = (c.i >> 16) & 1;
    c.i += 0x7fffu + lsb;   // round-to-nearest-even
    return (u16)(c.i >> 16);
}

// ---------------- kernel 1: normalize rows, write bf16 ----------------------
__global__ __launch_bounds__(256) void normalize_k(const float* __restrict__ zi,
                                                   const float* __restrict__ zj,
                                                   u16* __restrict__ zn) {
    const int row  = blockIdx.x * 4 + (threadIdx.x >> 6);
    const int lane = threadIdx.x & 63;
    const float* src = (row < HALF) ? (zi + (size_t)row * DIM)
                                    : (zj + (size_t)(row - HALF) * DIM);
    float4 v = reinterpret_cast<const float4*>(src)[lane];
    float ss = v.x * v.x + v.y * v.y + v.z * v.z + v.w * v.w;
    #pragma unroll
    for (int m = 32; m; m >>= 1) ss += __shfl_xor(ss, m);
    const float inv = 1.0f / fmaxf(sqrtf(ss), 1e-8f);
    ushort4 o;
    o.x = f2bf(v.x * inv); o.y = f2bf(v.y * inv);
    o.z = f2bf(v.z * inv); o.w = f2bf(v.w * inv);
    reinterpret_cast<ushort4*>(zn + (size_t)row * DIM)[lane] = o;
}

// ---------------- kernel 2: multi-tile triangular GEMM + exp + slab sums ----
// Each block processes TPB=4 consecutive triangle tiles as ONE 32-step
// double-buffered K-pipeline (stage crosses tile boundaries; epilogue every
// 8 steps hides the next chunk's load latency). slab[j][row]: unique slot per
// (tile-side, wave-half) -> no atomics, no init.
__device__ __forceinline__ void gload16(const void* g, void* lds) {
    __builtin_amdgcn_global_load_lds(
        (const __attribute__((address_space(1))) u32*)g,
        (__attribute__((address_space(3))) u32*)lds, 16, 0, 0);
}

__global__ __launch_bounds__(256, 3) void gemm_exp_rowsum(const u16* __restrict__ zn,
                                                          float* __restrict__ slab,
                                                          float* __restrict__ pos) {
    // XCD-aware bijective swizzle (520 = 8 * 65)
    const int b0  = blockIdx.x;
    const int blk = (b0 & 7) * (NBLK / 8) + (b0 >> 3);

    // decode first tile of this block, then advance through the triangle
    const int bstart = blk * TPB;
    int by = (int)((129.0f - sqrtf(129.0f * 129.0f - 8.0f * (float)bstart)) * 0.5f);
    while (by * (129 - by) / 2 > bstart) --by;
    while ((by + 1) * (129 - (by + 1)) / 2 <= bstart) ++by;
    int bx = by + (bstart - by * (129 - by) / 2);

    int rowBase[TPB], colBase[TPB];
    bool dg[TPB], ip[TPB];
    #pragma unroll
    for (int i = 0; i < TPB; ++i) {
        rowBase[i] = by * 128; colBase[i] = bx * 128;
        dg[i] = (by == bx);    ip[i] = (bx - by == 32);
        ++bx; if (bx >= NBT) { ++by; bx = by; }
    }

    __shared__ u16 As[2][128 * BK];   // 8 KiB per buf
    __shared__ u16 Bs[2][128 * BK];   // total LDS 32 KiB

    const int tid  = threadIdx.x;
    const int w    = tid >> 6;      // 0..3
    const int lane = tid & 63;
    const int wr = w >> 1;          // 0..1 -> 64-row strip
    const int wc = w & 1;           // 0..1 -> 64-col strip

    f32x4 acc[4][4] = {};

    // staging: LDS dest linear; source chunk pre-swizzled, key(row)=(row>>1)&3
    const int lr = lane >> 2;
    const int lc = (lane & 3) ^ ((lane >> 3) & 3);

    auto stage = [&](int buf, int ti, int kk) {
        #pragma unroll
        for (int s = 0; s < 2; ++s) {
            const int r0 = w * 32 + s * 16;   // wave-uniform
            gload16(zn + (size_t)(rowBase[ti] + r0 + lr) * DIM + kk + lc * 8,
                    &As[buf][r0 * BK]);
        }
        #pragma unroll
        for (int s = 0; s < 2; ++s) {
            const int r0 = w * 32 + s * 16;
            gload16(zn + (size_t)(colBase[ti] + r0 + lr) * DIM + kk + lc * 8,
                    &Bs[buf][r0 * BK]);
        }
    };

    // ds_read bases: chunk key depends only on lane&15
    const int chunk = ((lane >> 4) ^ (((lane & 15) >> 1) & 3)) * 16;
    const char* Ab = (const char*)&As[0][0] + (wr * 64 + (lane & 15)) * 64 + chunk;
    const char* Bb = (const char*)&Bs[0][0] + (wc * 64 + (lane & 15)) * 64 + chunk;

    auto compute = [&](int buf) {
        short8 af[4], bfr[4];
        #pragma unroll
        for (int mi = 0; mi < 4; ++mi)
            af[mi] = *reinterpret_cast<const short8*>(Ab + buf * 8192 + mi * 1024);
        #pragma unroll
        for (int ni = 0; ni < 4; ++ni)
            bfr[ni] = *reinterpret_cast<const short8*>(Bb + buf * 8192 + ni * 1024);
        __builtin_amdgcn_s_setprio(1);
        #pragma unroll
        for (int mi = 0; mi < 4; ++mi)
            #pragma unroll
            for (int ni = 0; ni < 4; ++ni)
                acc[mi][ni] = __builtin_amdgcn_mfma_f32_16x16x32_bf16(
                    af[mi], bfr[ni], acc[mi][ni], 0, 0, 0);
        __builtin_amdgcn_s_setprio(0);
    };

    auto epilogue = [&](int ti) {
        // C/D layout: col = lane&15, row = (lane>>4)*4 + v
        float cs[4] = {0.f, 0.f, 0.f, 0.f};
        float* rowSlot = slab + (size_t)((colBase[ti] >> 7) * 2 + wc) * NROWS
                         + rowBase[ti] + wr * 64;
        #pragma unroll
        for (int mi = 0; mi < 4; ++mi) {
            f32x4 rs = {0.f, 0.f, 0.f, 0.f};
            #pragma unroll
            for (int ni = 0; ni < 4; ++ni)
                #pragma unroll
                for (int v = 0; v < 4; ++v) {
                    const int R = wr * 64 + mi * 16 + (lane >> 4) * 4 + v;
                    const int C = wc * 64 + ni * 16 + (lane & 15);
                    float e = __expf(TEMP_INV * acc[mi][ni][v]);
                    if (dg[ti] && R == C) e = 0.f;   // exclude self-similarity
                    rs[v] += e;
                    cs[ni] += e;
                }
            #pragma unroll
            for (int v = 0; v < 4; ++v) {
                float s = rs[v];
                s += __shfl_xor(s, 1);
                s += __shfl_xor(s, 2);
                s += __shfl_xor(s, 4);
                s += __shfl_xor(s, 8);
                rs[v] = s;
            }
            if ((lane & 15) == 0)   // 4 lanes -> one coalesced 64B store
                *reinterpret_cast<f32x4*>(rowSlot + mi * 16 + (lane >> 4) * 4) = rs;
        }
        if (!dg[ti]) {
            float* colSlot = slab + (size_t)((rowBase[ti] >> 7) * 2 + wr) * NROWS
                             + colBase[ti] + wc * 64;
            #pragma unroll
            for (int ni = 0; ni < 4; ++ni) {
                float c = cs[ni];
                c += __shfl_xor(c, 16);
                c += __shfl_xor(c, 32);
                if (lane < 16)
                    colSlot[ni * 16 + lane] = c;
            }
        }
        if (ip[ti]) {
            #pragma unroll
            for (int mi = 0; mi < 4; ++mi)
                #pragma unroll
                for (int ni = 0; ni < 4; ++ni)
                    #pragma unroll
                    for (int v = 0; v < 4; ++v) {
                        const int R = wr * 64 + mi * 16 + (lane >> 4) * 4 + v;
                        const int C = wc * 64 + ni * 16 + (lane & 15);
                        if (R == C) {
                            const float val = acc[mi][ni][v];
                            pos[rowBase[ti] + R] = val;
                            pos[rowBase[ti] + R + HALF] = val;
                        }
                    }
        }
        // reset accumulators for next tile
        #pragma unroll
        for (int mi = 0; mi < 4; ++mi)
            #pragma unroll
            for (int ni = 0; ni < 4; ++ni)
                acc[mi][ni] = f32x4{0.f, 0.f, 0.f, 0.f};
    };

    // 32-step pipeline: chunk u lives in buf u&1; stage(u+2) issued while
    // computing u; counted vmcnt never 0 mid-loop.
    stage(0, 0, 0);
    stage(1, 0, BK);
    WAITV(4);  BARRIER();
    #pragma unroll
    for (int u = 0; u < 32; ++u) {
        compute(u & 1);
        if ((u & 7) == 7) epilogue(u >> 3);   // hides next chunk's load latency
        if (u < 30) {
            BARRIER();                         // all waves done reading buf u&1
            stage(u & 1, (u + 2) >> 3, ((u + 2) & 7) * BK);
            WAITV(4);  BARRIER();              // chunk u+1 landed
        } else if (u == 30) {
            WAITV(0);  BARRIER();              // last chunk landed
        }
    }
}

// ---------------- kernel 3: reduce slab rows -> per-block partials ----------
__global__ __launch_bounds__(256) void finalize_k(const float* __restrict__ slab,
                                                  const float* __restrict__ pos,
                                                  float* __restrict__ part) {
    const int row = blockIdx.x * 256 + threadIdx.x;
    float d = 0.f;
    #pragma unroll 8
    for (int j = 0; j < NSLAB; ++j)
        d += slab[(size_t)j * NROWS + row];    // coalesced across threads
    float s = logf(d) - TEMP_INV * pos[row];
    __shared__ float red[256];
    red[threadIdx.x] = s;
    __syncthreads();
    #pragma unroll
    for (int m = 128; m; m >>= 1) {
        if (threadIdx.x < m) red[threadIdx.x] += red[threadIdx.x + m];
        __syncthreads();
    }
    if (threadIdx.x == 0) part[blockIdx.x] = red[0];
}

// ---------------- kernel 4: sum 32 partials (deterministic, no atomics) -----
__global__ __launch_bounds__(64) void sum_k(const float* __restrict__ part,
                                            float* __restrict__ out) {
    float v = (threadIdx.x < 32) ? part[threadIdx.x] : 0.f;
    #pragma unroll
    for (int m = 32; m; m >>= 1) v += __shfl_xor(v, m);
    if (threadIdx.x == 0) out[0] = v * (1.0f / NROWS);
}

extern "C" void kernel_launch(void* const* d_in, const int* in_sizes, int n_in,
                              void* d_out, int out_size, void* d_ws, size_t ws_size,
                              hipStream_t stream) {
    const float* zi = (const float*)d_in[0];
    const float* zj = (const float*)d_in[1];
    float* out = (float*)d_out;

    // workspace: zn bf16 [8192][256] (4 MiB) | slab f32 [128][8192] (4 MiB)
    //            | pos f32 [8192] | part f32 [32]
    u16*   zn   = (u16*)d_ws;
    float* slab = (float*)((char*)d_ws + (size_t)NROWS * DIM * sizeof(u16));
    float* pos  = slab + (size_t)NSLAB * NROWS;
    float* part = pos + NROWS;

    normalize_k<<<NROWS / 4, 256, 0, stream>>>(zi, zj, zn);
    gemm_exp_rowsum<<<NBLK, 256, 0, stream>>>(zn, slab, pos);
    finalize_k<<<NROWS / 256, 256, 0, stream>>>(slab, pos, part);
    sum_k<<<1, 64, 0, stream>>>(part, out);
}